// Round 1
// baseline (2005.717 us; speedup 1.0000x reference)
//
#include <hip/hip_runtime.h>
#include <stdint.h>

typedef unsigned long long u64;
typedef unsigned int u32;

#define NPTS    131072
#define NBATCH  16
#define NSAMP   1024
#define SUBS    16                 // blocks per batch
#define THREADS 256
#define PPT     32                 // points per thread: 131072 / (16*256)
#define CHUNK   (PPT * THREADS)    // 8192 points per block

// Packed candidate word: [ tag:10 bits (bits 49..58) | key:32 bits (17..48) | ~idx:17 bits (0..16) ]
// key = 0 for cand==-1 (masked-out), else float_bits(val)+1 (monotone for val>=0).
// Larger packed (same tag) == better candidate; ~idx makes smaller index win ties (first-max).

__global__ __launch_bounds__(THREADS, 1)
void fps_kernel(const float* __restrict__ x, float* __restrict__ y, u64* __restrict__ slots)
{
    const int bid   = blockIdx.x;
    const int batch = bid & (NBATCH - 1);   // consecutive bids round-robin XCDs -> a batch's 16 blocks share an XCD
    const int sub   = bid >> 4;             // 0..15 within batch
    const int tid   = threadIdx.x;
    const int lane  = tid & 63;
    const int wv    = tid >> 6;

    const float* __restrict__ xb = x + (size_t)batch * (NPTS * 3);
    const int gbase = sub * CHUNK;

    // register-resident points + running min distance (static indexing only!)
    float px_[PPT], py_[PPT], pz_[PPT], t_[PPT];

#pragma unroll
    for (int k = 0; k < PPT; ++k) {
        const int g = gbase + k * THREADS + tid;
        const float a = xb[3 * g + 0];
        const float b = xb[3 * g + 1];
        const float c = xb[3 * g + 2];
        px_[k] = a; py_[k] = b; pz_[k] = c;
        // mag exactly as reference: ((a*a + b*b) + c*c), no FMA contraction
        const float mag = __fadd_rn(__fadd_rn(__fmul_rn(a, a), __fmul_rn(b, b)), __fmul_rn(c, c));
        // unmasked points: cand == -1 forever (min(-1, d>=0) == -1)
        t_[k] = (mag > 1e-3f) ? 1e10f : -1.0f;
    }

    __shared__ u64   s_red[4];
    __shared__ float s_p[3];

    // first selected point is always index 0
    float cpx = xb[0], cpy = xb[1], cpz = xb[2];
    if (sub == 0 && tid == 0) {
        float* yo = y + (size_t)batch * (NSAMP * 3);
        yo[0] = cpx; yo[1] = cpy; yo[2] = cpz;
    }

    for (int it = 1; it < NSAMP; ++it) {
        // ---- update temps against current point, track thread-local argmax ----
        float bv = -2.0f;
        int   bk = 0;
#pragma unroll
        for (int k = 0; k < PPT; ++k) {
            const float dx = __fsub_rn(px_[k], cpx);
            const float dy = __fsub_rn(py_[k], cpy);
            const float dz = __fsub_rn(pz_[k], cpz);
            const float d  = __fadd_rn(__fadd_rn(__fmul_rn(dx, dx), __fmul_rn(dy, dy)),
                                       __fmul_rn(dz, dz));
            const float tn = fminf(t_[k], d);
            t_[k] = tn;
            if (tn > bv) { bv = tn; bk = k; }   // strict > keeps smallest k (ascending global idx)
        }
        const int gidx = gbase + bk * THREADS + tid;
        const u32 key  = (bv < 0.0f) ? 0u : (__float_as_uint(bv) + 1u);
        u64 packed = ((u64)(u32)it << 49) | ((u64)key << 17) | (u32)(131071 - gidx);

        // ---- block reduce (max of packed == best candidate, first-max tiebreak) ----
#pragma unroll
        for (int off = 32; off; off >>= 1) {
            const u64 o = __shfl_xor(packed, off);
            if (o > packed) packed = o;
        }
        if (lane == 0) s_red[wv] = packed;
        __syncthreads();

        if (wv == 0) {
            if (lane == 0) {
                u64 pk = s_red[0];
                if (s_red[1] > pk) pk = s_red[1];
                if (s_red[2] > pk) pk = s_red[2];
                if (s_red[3] > pk) pk = s_red[3];
                u64* sp = slots + (size_t)(((it & 1) * NBATCH + batch) * SUBS + sub);
                __hip_atomic_store(sp, pk, __ATOMIC_RELAXED, __HIP_MEMORY_SCOPE_AGENT);
            }
            // ---- poll all 16 sibling slots for this iteration's tag ----
            u64* sp2 = slots + (size_t)((it & 1) * NBATCH + batch) * SUBS + (lane & 15);
            u64 v;
            do {
                v = __hip_atomic_load(sp2, __ATOMIC_RELAXED, __HIP_MEMORY_SCOPE_AGENT);
            } while ((u32)(v >> 49) != (u32)it);
            // max over the 16 slots (offsets 8..1 stay within each 16-lane group)
#pragma unroll
            for (int off = 8; off; off >>= 1) {
                const u64 o = __shfl_xor(v, off);
                if (o > v) v = o;
            }
            if (lane == 0) {
                const int widx = 131071 - (int)(v & 0x1FFFF);
                const float wx = xb[3 * widx + 0];
                const float wy = xb[3 * widx + 1];
                const float wz = xb[3 * widx + 2];
                s_p[0] = wx; s_p[1] = wy; s_p[2] = wz;
                if (sub == 0) {
                    float* yo = y + ((size_t)batch * NSAMP + it) * 3;
                    yo[0] = wx; yo[1] = wy; yo[2] = wz;
                }
            }
        }
        __syncthreads();
        cpx = s_p[0]; cpy = s_p[1]; cpz = s_p[2];
    }
}

extern "C" void kernel_launch(void* const* d_in, const int* in_sizes, int n_in,
                              void* d_out, int out_size, void* d_ws, size_t ws_size,
                              hipStream_t stream) {
    const float* x = (const float*)d_in[0];
    float* y       = (float*)d_out;
    u64* slots     = (u64*)d_ws;   // needs 2 * 16 * 16 * 8 = 4 KiB

    // zero slot tags so no stale tag can match (tags used are 1..1023)
    hipMemsetAsync(d_ws, 0, (size_t)(2 * NBATCH * SUBS * sizeof(u64)), stream);

    void* args[] = { (void*)&x, (void*)&y, (void*)&slots };
    hipLaunchCooperativeKernel((void*)fps_kernel,
                               dim3(NBATCH * SUBS), dim3(THREADS),
                               args, 0, stream);
}